// Round 1
// baseline (304.572 us; speedup 1.0000x reference)
//
#include <hip/hip_runtime.h>
#include <math.h>

typedef unsigned short ushort_t;
typedef __attribute__((ext_vector_type(4))) float floatx4;
typedef __attribute__((ext_vector_type(8))) short shortx8;
typedef __attribute__((ext_vector_type(8))) unsigned short ushortx8;

__device__ __forceinline__ float bf2f(ushort_t h) {
    union { unsigned u; float f; } x; x.u = ((unsigned)h) << 16; return x.f;
}
__device__ __forceinline__ ushort_t f2bf(float f) {
    union { float f; unsigned u; } x; x.f = f;
    unsigned r = x.u + 0x7fffu + ((x.u >> 16) & 1u);
    return (ushort_t)(r >> 16);
}
__device__ __forceinline__ float rdIn(const void* p, size_t i, int f32) {
    return f32 ? ((const float*)p)[i] : bf2f(((const ushort_t*)p)[i]);
}
// async global->LDS DMA, 16 B per lane (dest must be wave-uniform base + lane*16)
__device__ __forceinline__ void gload16(const ushort_t* g, ushort_t* l) {
    __builtin_amdgcn_global_load_lds(
        (const __attribute__((address_space(1))) unsigned int*)g,
        (__attribute__((address_space(3))) unsigned int*)l, 16, 0, 0);
}
// branch-free GELU: erf via Abramowitz-Stegun 7.1.26 (|erf err| <= 1.5e-7)
__device__ __forceinline__ float gelu_f(float v) {
    float z = fabsf(v) * 0.70710678118654752f;
    float t = __builtin_amdgcn_rcpf(1.0f + 0.3275911f * z);
    float p = 1.061405429f;
    p = p * t - 1.453152027f;
    p = p * t + 1.421413741f;
    p = p * t - 0.284496736f;
    p = p * t + 0.254829592f;
    p = p * t;
    float er = 1.0f - p * __expf(-z * z);
    er = copysignf(er, v);
    return 0.5f * v * (1.0f + er);
}

// ---------------- dtype detect: bf16 vs fp32 --------------------------------
__global__ __launch_bounds__(256) void detect_kernel(const ushort_t* __restrict__ x,
                                                     int* __restrict__ flag) {
    __shared__ int cnt;
    if (threadIdx.x == 0) cnt = 0;
    __syncthreads();
    ushort_t v = x[threadIdx.x];
    int e = (v >> 7) & 0xff;
    int ok = (e >= 100 && e <= 150) || (v == 0);
    atomicAdd(&cnt, ok);
    __syncthreads();
    if (threadIdx.x == 0) flag[0] = (cnt >= 240) ? 0 : 1;   // 0=bf16, 1=fp32
}

// ---------------- prep: x [2,4095,512] raw -> Xp [2,4096,512] bf16 ----------
__global__ __launch_bounds__(256) void prep_kernel(const void* __restrict__ x,
                                                   ushort_t* __restrict__ Xp,
                                                   const int* __restrict__ flag) {
    const int f32 = flag[0];
    int i = blockIdx.x * 256 + threadIdx.x;
    int e = i * 8;
    int s = (e >> 9) & 4095;
    int b = e >> 21;
    ushortx8 val = {0, 0, 0, 0, 0, 0, 0, 0};
    if (s < 4095) {
        size_t src = ((size_t)(b * 4095 + s) << 9) + (e & 511);
        if (f32) {
            const float* p = (const float*)x + src;
            floatx4 a = *(const floatx4*)p;
            floatx4 c = *(const floatx4*)(p + 4);
            val[0] = f2bf(a[0]); val[1] = f2bf(a[1]); val[2] = f2bf(a[2]); val[3] = f2bf(a[3]);
            val[4] = f2bf(c[0]); val[5] = f2bf(c[1]); val[6] = f2bf(c[2]); val[7] = f2bf(c[3]);
        } else {
            val = *(const ushortx8*)((const ushort_t*)x + src);
        }
    }
    *(ushortx8*)&Xp[e] = val;
}

// ---------------- transpose raw weight [R,C] -> bf16 [C,R] ------------------
__global__ __launch_bounds__(256) void transpose_kernel(
    const void* __restrict__ in0, const void* __restrict__ in1,
    const void* __restrict__ in2, ushort_t* __restrict__ out,
    int R, int C, const int* __restrict__ flag) {
    const int f32 = flag[0];
    const int z = blockIdx.z;
    const void* in = (z == 0) ? in0 : (z == 1) ? in1 : in2;
    __shared__ ushort_t tile[32][33];
    int c0 = blockIdx.x * 32, r0 = blockIdx.y * 32;
    int tx = threadIdx.x & 31, ty = threadIdx.x >> 5;
#pragma unroll
    for (int i = 0; i < 4; i++) {
        size_t idx = (size_t)(r0 + ty + 8 * i) * C + c0 + tx;
        tile[ty + 8 * i][tx] = f32 ? f2bf(((const float*)in)[idx])
                                   : ((const ushort_t*)in)[idx];
    }
    __syncthreads();
#pragma unroll
    for (int i = 0; i < 4; i++)
        out[(size_t)z * R * C + (size_t)(c0 + ty + 8 * i) * R + r0 + tx] =
            tile[tx][ty + 8 * i];
}

// ---------------- legacy GEMM (kept for MLP2, N=512): C = A @ Bt^T ----------
#define BM 128
#define BK 32

template<int TBN>
__global__ __launch_bounds__(256) void gemm_bt_kernel(
    const ushort_t* __restrict__ A, const ushort_t* __restrict__ Bt,
    const void* __restrict__ bias0, const void* __restrict__ bias1,
    const void* __restrict__ bias2, void* outp,
    int M, int N, int K, float scale, int epi,
    const ushort_t* __restrict__ resid, const int* __restrict__ flag) {
    constexpr int TN = TBN / 32;             // col tiles per wave
    const int f32 = flag[0];
    __shared__ __align__(16) ushort_t As[2][BM][BK];
    __shared__ __align__(16) ushort_t Bs[2][TBN][BK];
    const int m0 = blockIdx.x * BM, n0 = blockIdx.y * TBN;
    const int t = threadIdx.x;
    const int lane = t & 63, wave = t >> 6;
    const int wr = wave >> 1, wc = wave & 1;
    const int quad = lane >> 4, l16 = lane & 15;
    const int srow = t >> 2, schunk = (t & 3) * 8;

    const ushort_t* Ag = A + (size_t)(m0 + srow) * K + schunk;
    const ushort_t* Bg = Bt + (size_t)(n0 + srow) * K + schunk;

    floatx4 acc[4][TN];
#pragma unroll
    for (int i = 0; i < 4; i++)
#pragma unroll
        for (int j = 0; j < TN; j++)
#pragma unroll
            for (int r = 0; r < 4; r++) acc[i][j][r] = 0.f;

    // preload tile 0 into buf 0
    gload16(Ag,                  &As[0][srow][schunk]);
    gload16(Ag + (size_t)64 * K, &As[0][srow + 64][schunk]);
    gload16(Bg,                  &Bs[0][srow][schunk]);
    if (TBN == 128)
        gload16(Bg + (size_t)64 * K, &Bs[0][srow + 64][schunk]);

    const int KT = K / BK;
    for (int kt = 0; kt < KT; kt++) {
        __syncthreads();
        if (kt + 1 < KT) {
            int nb = (kt + 1) & 1;
            const ushort_t* Ag2 = Ag + (kt + 1) * BK;
            const ushort_t* Bg2 = Bg + (kt + 1) * BK;
            gload16(Ag2,                  &As[nb][srow][schunk]);
            gload16(Ag2 + (size_t)64 * K, &As[nb][srow + 64][schunk]);
            gload16(Bg2,                  &Bs[nb][srow][schunk]);
            if (TBN == 128)
                gload16(Bg2 + (size_t)64 * K, &Bs[nb][srow + 64][schunk]);
        }
        const int cb = kt & 1;
        shortx8 af[4], bfr[TN];
#pragma unroll
        for (int tm = 0; tm < 4; tm++)
            af[tm] = *(const shortx8*)&As[cb][wr * 64 + tm * 16 + l16][quad * 8];
#pragma unroll
        for (int tn = 0; tn < TN; tn++)
            bfr[tn] = *(const shortx8*)&Bs[cb][wc * (TBN / 2) + tn * 16 + l16][quad * 8];
#pragma unroll
        for (int tm = 0; tm < 4; tm++)
#pragma unroll
            for (int tn = 0; tn < TN; tn++)
                acc[tm][tn] = __builtin_amdgcn_mfma_f32_16x16x32_bf16(
                    af[tm], bfr[tn], acc[tm][tn], 0, 0, 0);
    }

#pragma unroll
    for (int tm = 0; tm < 4; tm++) {
#pragma unroll
        for (int tn = 0; tn < TN; tn++) {
#pragma unroll
            for (int r = 0; r < 4; r++) {
                int m = m0 + wr * 64 + tm * 16 + quad * 4 + r;
                int n = n0 + wc * (TBN / 2) + tn * 16 + l16;
                float v = acc[tm][tn][r];
                if (epi == 3) {
                    int idx = n >> 9, off = n & 511;
                    const void* bp = (idx == 0) ? bias0 : (idx == 1) ? bias1 : bias2;
                    float bb = rdIn(bp, off, f32);
                    float sc = (idx == 0) ? scale : 1.0f;
                    ((ushort_t*)outp)[(size_t)idx * 4194304 + (size_t)m * 512 + off] =
                        f2bf((v + bb) * sc);
                } else if (epi == 1) {
                    v += rdIn(bias0, n, f32);
                    ((ushort_t*)outp)[(size_t)m * N + n] = f2bf(gelu_f(v));
                } else {
                    int bb2 = m >> 12, s = m & 4095;
                    if (s < 4095) {
                        v += rdIn(bias0, n, f32) + bf2f(resid[(size_t)m * N + n]);
                        size_t oidx = ((size_t)bb2 * 4095 + s) * (size_t)N + n;
                        if (f32) ((float*)outp)[oidx] = v;
                        else     ((ushort_t*)outp)[oidx] = f2bf(v);
                    }
                }
            }
        }
    }
}

// ---------------- pipelined 256x256 GEMM (K=512 layers: QKV, MLP1) ----------
// 512 threads = 8 waves (2x4), wave tile 128x64, BK=32.
// 4-deep LDS ring buffer; counted vmcnt (8 steady) + raw s_barrier: loads for
// tile t+3 stay in flight across barriers, never drained to 0 in main loop.
// LDS chunk-XOR swizzle (chunk ^= row&3), applied BOTH at the global source
// address (gload_lds writes linearly) and at the ds_read chunk -> the wave's
// 64-lane b128 read is a bijection over a 1KB region: bank-conflict-free.
// EPI 1: out[m,n] = gelu(acc + bias0[n])  (bf16)
// EPI 3: QKV merged: idx=n>>9, off=n&511; out + idx*4194304 + m*512 + off
template<int EPI>
__global__ __launch_bounds__(512, 2) void gemm256_kernel(
    const ushort_t* __restrict__ A, const ushort_t* __restrict__ Bt,
    const void* __restrict__ bias0, const void* __restrict__ bias1,
    const void* __restrict__ bias2, void* outp,
    int M, int N, int K, float scale, const int* __restrict__ flag) {
    const int f32 = flag[0];
    __shared__ __align__(16) ushort_t As[4][256][32];
    __shared__ __align__(16) ushort_t Bs[4][256][32];
    const int m0 = blockIdx.x * 256, n0 = blockIdx.y * 256;
    const int t = threadIdx.x;
    const int lane = t & 63, wave = t >> 6;
    const int wr = wave >> 2, wc = wave & 3;        // 2 x 4 wave grid
    const int l16 = lane & 15, quad = lane >> 4;
    const int sw = (quad ^ (l16 & 3)) * 8;          // swizzled read chunk (ushorts)

    // staging: thread t covers row sr (0..127) chunk (t&3); source chunk swizzled
    const int sr = t >> 2;
    const int sc = ((t & 3) ^ (sr & 3)) * 8;
    const ushort_t* Ag = A + (size_t)(m0 + sr) * K + sc;
    const ushort_t* Bg = Bt + (size_t)(n0 + sr) * K + sc;
    ushort_t* Ad = &As[0][0][0] + t * 8;            // linear dest: base + t*16B
    ushort_t* Bd = &Bs[0][0][0] + t * 8;

    auto STAGE = [&](int kt) {
        const int b = kt & 3;
        const ushort_t* ga = Ag + kt * 32;
        const ushort_t* gb = Bg + kt * 32;
        gload16(ga,                   Ad + b * 8192);
        gload16(ga + (size_t)128 * K, Ad + b * 8192 + 4096);
        gload16(gb,                   Bd + b * 8192);
        gload16(gb + (size_t)128 * K, Bd + b * 8192 + 4096);
    };

    floatx4 acc[8][4];
#pragma unroll
    for (int i = 0; i < 8; i++)
#pragma unroll
        for (int j = 0; j < 4; j++)
#pragma unroll
            for (int r = 0; r < 4; r++) acc[i][j][r] = 0.f;

    const int KT = K / 32;
    STAGE(0);
    if (KT > 1) STAGE(1);
    if (KT > 2) STAGE(2);

    for (int kt = 0; kt < KT; kt++) {
        // wait until tile kt landed; allow tiles kt+1..kt+2 (8 loads) in flight
        if (kt + 3 <= KT)      asm volatile("s_waitcnt vmcnt(8)" ::: "memory");
        else if (kt + 2 == KT) asm volatile("s_waitcnt vmcnt(4)" ::: "memory");
        else                   asm volatile("s_waitcnt vmcnt(0)" ::: "memory");
        __builtin_amdgcn_s_barrier();
        asm volatile("" ::: "memory");
        if (kt + 3 < KT) STAGE(kt + 3);             // overwrites buf[(kt-1)&3]: reads done

        const int b = kt & 3;
        shortx8 bfr[4];
#pragma unroll
        for (int nf = 0; nf < 4; nf++)
            bfr[nf] = *(const shortx8*)&Bs[b][wc * 64 + nf * 16 + l16][sw];
#pragma unroll
        for (int mf = 0; mf < 8; mf++) {
            shortx8 af = *(const shortx8*)&As[b][wr * 128 + mf * 16 + l16][sw];
#pragma unroll
            for (int nf = 0; nf < 4; nf++)
                acc[mf][nf] = __builtin_amdgcn_mfma_f32_16x16x32_bf16(
                    af, bfr[nf], acc[mf][nf], 0, 0, 0);
        }
    }

#pragma unroll
    for (int mf = 0; mf < 8; mf++) {
#pragma unroll
        for (int nf = 0; nf < 4; nf++) {
#pragma unroll
            for (int r = 0; r < 4; r++) {
                int m = m0 + wr * 128 + mf * 16 + quad * 4 + r;
                int n = n0 + wc * 64 + nf * 16 + l16;
                float v = acc[mf][nf][r];
                if (EPI == 3) {
                    int idx = n >> 9, off = n & 511;
                    const void* bp = (idx == 0) ? bias0 : (idx == 1) ? bias1 : bias2;
                    float bb = rdIn(bp, off, f32);
                    float scl = (idx == 0) ? scale : 1.0f;
                    ((ushort_t*)outp)[(size_t)idx * 4194304 + (size_t)m * 512 + off] =
                        f2bf((v + bb) * scl);
                } else {
                    v += rdIn(bias0, n, f32);
                    ((ushort_t*)outp)[(size_t)m * N + n] = f2bf(gelu_f(v));
                }
            }
        }
    }
}

// ---------------- MFMA windowed attention + global key ----------------------
#define ALD 344

__global__ __launch_bounds__(256) void attn_mfma_kernel(
    ushort_t* Q, const ushort_t* __restrict__ Kx, const ushort_t* __restrict__ Vx) {
    __shared__ ushort_t Pl[64][ALD];
    __shared__ ushort_t Vt[2][64][40];
    __shared__ float pgl[64];

    const int t = threadIdx.x;
    const int lane = t & 63, w = t >> 6;
    const int l16 = lane & 15, quad = lane >> 4;
    const int bid = blockIdx.x;
    const int qt = bid & 63;
    const int h = (bid >> 6) & 7;
    const int b = bid >> 9;
    const int q0 = qt * 64;
    const int jmin = q0 - 128;
    const size_t base = ((size_t)b * 4096) * 512 + (size_t)h * 64;

    const int qw = q0 + w * 16;
    const int lo = qw - 128, hi = qw + 15 + 128;

    shortx8 qf0, qf1;
    {
        const ushort_t* qp = Q + base + (size_t)(qw + l16) * 512 + quad * 8;
        qf0 = *(const shortx8*)(qp);
        qf1 = *(const shortx8*)(qp + 32);
    }

    floatx4 s[21];
#pragma unroll
    for (int i = 0; i < 21; i++)
#pragma unroll
        for (int r = 0; r < 4; r++) s[i][r] = 0.f;

#pragma unroll
    for (int tt = 0; tt < 20; tt++) {
        int jt = jmin + tt * 16;
        if (jt + 15 < lo || jt > hi) continue;
        int key = jt + l16;
        int kcl = min(max(key, 0), 4094);
        const ushort_t* kp = Kx + base + (size_t)kcl * 512 + quad * 8;
        shortx8 k0 = *(const shortx8*)(kp);
        shortx8 k1 = *(const shortx8*)(kp + 32);
        s[tt] = __builtin_amdgcn_mfma_f32_16x16x32_bf16(qf0, k0, s[tt], 0, 0, 0);
        s[tt] = __builtin_amdgcn_mfma_f32_16x16x32_bf16(qf1, k1, s[tt], 0, 0, 0);
    }
    {
        const ushort_t* kp = Kx + base + (size_t)4095 * 512 + quad * 8;
        shortx8 k0 = *(const shortx8*)(kp);
        shortx8 k1 = *(const shortx8*)(kp + 32);
        s[20] = __builtin_amdgcn_mfma_f32_16x16x32_bf16(qf0, k0, s[20], 0, 0, 0);
        s[20] = __builtin_amdgcn_mfma_f32_16x16x32_bf16(qf1, k1, s[20], 0, 0, 0);
    }

#pragma unroll
    for (int tt = 0; tt < 20; tt++) {
        int j = jmin + tt * 16 + l16;
        bool okj = (j >= 0) && (j <= 4094);
#pragma unroll
        for (int r = 0; r < 4; r++) {
            int q = qw + quad * 4 + r;
            bool ok = okj && (j - q <= 128) && (q - j <= 128);
            if (!ok) s[tt][r] = -1e30f;
        }
    }
    if (l16 != 0) {
#pragma unroll
        for (int r = 0; r < 4; r++) s[20][r] = -1e30f;
    }

    floatx4 mx = s[0];
#pragma unroll
    for (int tt = 1; tt < 21; tt++)
#pragma unroll
        for (int r = 0; r < 4; r++) mx[r] = fmaxf(mx[r], s[tt][r]);
#pragma unroll
    for (int off = 1; off < 16; off <<= 1)
#pragma unroll
        for (int r = 0; r < 4; r++) mx[r] = fmaxf(mx[r], __shfl_xor(mx[r], off, 64));

    floatx4 sum;
#pragma unroll
    for (int r = 0; r < 4; r++) sum[r] = 0.f;
#pragma unroll
    for (int tt = 0; tt < 21; tt++)
#pragma unroll
        for (int r = 0; r < 4; r++) {
            float e = __expf(s[tt][r] - mx[r]);
            s[tt][r] = e;
            sum[r] += e;
        }
#pragma unroll
    for (int off = 1; off < 16; off <<= 1)
#pragma unroll
        for (int r = 0; r < 4; r++) sum[r] += __shfl_xor(sum[r], off, 64);

    floatx4 inv;
#pragma unroll
    for (int r = 0; r < 4; r++) inv[r] = 1.f / sum[r];

#pragma unroll
    for (int tt = 0; tt < 20; tt++)
#pragma unroll
        for (int r = 0; r < 4; r++)
            Pl[w * 16 + quad * 4 + r][tt * 16 + l16] = f2bf(s[tt][r]);
    if (l16 == 0) {
#pragma unroll
        for (int r = 0; r < 4; r++) pgl[w * 16 + quad * 4 + r] = s[20][r];
    }

    floatx4 o[4];
#pragma unroll
    for (int nt = 0; nt < 4; nt++)
#pragma unroll
        for (int r = 0; r < 4; r++) o[nt][r] = 0.f;

    const int ck = t & 31, cd = t >> 5;
    ushortx8 vreg;
    {
        int row = min(max(jmin + ck, 0), 4095);
        vreg = *(const ushortx8*)&Vx[base + (size_t)row * 512 + cd * 8];
    }
    for (int c = 0; c < 10; c++) {
#pragma unroll
        for (int e = 0; e < 8; e++) Vt[c & 1][cd * 8 + e][ck] = vreg[e];
        if (c < 9) {
            int row = min(max(jmin + (c + 1) * 32 + ck, 0), 4095);
            vreg = *(const ushortx8*)&Vx[base + (size_t)row * 512 + cd * 8];
        }
        __syncthreads();
        int jc = jmin + c * 32;
        if (jc + 31 >= lo && jc <= hi) {
            shortx8 pf = *(const shortx8*)&Pl[w * 16 + l16][c * 32 + quad * 8];
#pragma unroll
            for (int nt = 0; nt < 4; nt++) {
                shortx8 vf = *(const shortx8*)&Vt[c & 1][nt * 16 + l16][quad * 8];
                o[nt] = __builtin_amdgcn_mfma_f32_16x16x32_bf16(pf, vf, o[nt], 0, 0, 0);
            }
        }
    }

#pragma unroll
    for (int nt = 0; nt < 4; nt++) {
        float vg = bf2f(Vx[base + (size_t)4095 * 512 + nt * 16 + l16]);
#pragma unroll
        for (int r = 0; r < 4; r++) {
            float pg = pgl[w * 16 + quad * 4 + r];
            float val = (o[nt][r] + pg * vg) * inv[r];
            Q[base + (size_t)(qw + quad * 4 + r) * 512 + nt * 16 + l16] = f2bf(val);
        }
    }
}

// ---------------- residual + LayerNorm, in-place on hio ---------------------
__global__ __launch_bounds__(256) void ln_kernel(
    const void* __restrict__ x, ushort_t* hio,
    const void* __restrict__ g, const void* __restrict__ bta,
    const int* __restrict__ flag) {
    const int f32 = flag[0];
    const int r = blockIdx.x;
    const int b = (r >= 4095) ? 1 : 0;
    const int s = r - b * 4095;
    const size_t xrow = (size_t)r * 512;
    const size_t hrow = ((size_t)b * 4096 + s) * 512;
    const int t = threadIdx.x;
    float h0 = rdIn(x, xrow + t, f32) + bf2f(hio[hrow + t]);
    float h1 = rdIn(x, xrow + 256 + t, f32) + bf2f(hio[hrow + 256 + t]);
    float sum = h0 + h1, sq = h0 * h0 + h1 * h1;
#pragma unroll
    for (int off = 1; off < 64; off <<= 1) {
        sum += __shfl_xor(sum, off, 64);
        sq += __shfl_xor(sq, off, 64);
    }
    __shared__ float red[8];
    int wave = t >> 6, lane = t & 63;
    if (lane == 0) { red[wave] = sum; red[wave + 4] = sq; }
    __syncthreads();
    sum = red[0] + red[1] + red[2] + red[3];
    sq = red[4] + red[5] + red[6] + red[7];
    float mu = sum * (1.f / 512.f);
    float var = sq * (1.f / 512.f) - mu * mu;
    float rs = rsqrtf(var + 1e-5f);
    float v0 = (h0 - mu) * rs * rdIn(g, t, f32) + rdIn(bta, t, f32);
    float v1 = (h1 - mu) * rs * rdIn(g, 256 + t, f32) + rdIn(bta, 256 + t, f32);
    hio[hrow + t] = f2bf(v0);
    hio[hrow + 256 + t] = f2bf(v1);
}

// ---------------- launch -----------------------------------------------------
// ws layout (peak 47,710,212 B; ws_size proven >= this in round 5/6):
//   Qb[0) Kb[8.39M) Vb[16.78M)
//   Xp[33.55M..41.94M)  bf16 x, dead after QKV GEMM
//   Gs[8.39M..41.94M)   MLP strip, written after Xp is dead
//   Wqt[41.94M) W1t[43.52M) W2t[45.61M) flag[47.71M)
extern "C" void kernel_launch(void* const* d_in, const int* in_sizes, int n_in,
                              void* d_out, int out_size, void* d_ws, size_t ws_size,
                              hipStream_t stream) {
    const void* x   = d_in[0];
    const void* Wq  = d_in[2];
    const void* bq  = d_in[3];
    const void* Wk  = d_in[4];
    const void* bk  = d_in[5];
    const void* Wv  = d_in[6];
    const void* bv  = d_in[7];
    const void* lng = d_in[14];
    const void* lnb = d_in[15];
    const void* W1  = d_in[16];
    const void* b1  = d_in[17];
    const void* W2  = d_in[18];
    const void* b2  = d_in[19];

    char* ws = (char*)d_ws;
    ushort_t* Qb  = (ushort_t*)(ws + 0);
    ushort_t* Kb  = (ushort_t*)(ws + 8388608);
    ushort_t* Vb  = (ushort_t*)(ws + 16777216);
    ushort_t* Xp  = (ushort_t*)(ws + 33554432);
    ushort_t* Gs  = (ushort_t*)(ws + 8388608);
    ushort_t* Wqt = (ushort_t*)(ws + 41943040);
    ushort_t* W1t = (ushort_t*)(ws + 43515904);
    ushort_t* W2t = (ushort_t*)(ws + 45613056);
    int*      flg = (int*)(ws + 47710208);

    detect_kernel<<<dim3(1), dim3(256), 0, stream>>>((const ushort_t*)x, flg);

    transpose_kernel<<<dim3(16, 16, 3), dim3(256), 0, stream>>>(Wq, Wk, Wv, Wqt, 512, 512, flg);
    transpose_kernel<<<dim3(64, 16, 1), dim3(256), 0, stream>>>(W1, W1, W1, W1t, 512, 2048, flg);
    transpose_kernel<<<dim3(16, 64, 1), dim3(256), 0, stream>>>(W2, W2, W2, W2t, 2048, 512, flg);

    prep_kernel<<<dim3(2048), dim3(256), 0, stream>>>(x, Xp, flg);

    const float scale = 0.125f;  // 1/sqrt(64)
    gemm256_kernel<3><<<dim3(32, 6), dim3(512), 0, stream>>>(
        Xp, Wqt, bq, bk, bv, Qb, 8192, 1536, 512, scale, flg);

    attn_mfma_kernel<<<dim3(1024), dim3(256), 0, stream>>>(Qb, Kb, Vb);

    ln_kernel<<<dim3(8190), dim3(256), 0, stream>>>(x, Qb, lng, lnb, flg);

    gemm256_kernel<1><<<dim3(32, 8), dim3(512), 0, stream>>>(
        Qb, W1t, b1, b1, b1, Gs, 8192, 2048, 512, 1.0f, flg);
    gemm_bt_kernel<64><<<dim3(64, 8), dim3(256), 0, stream>>>(
        Gs, W2t, b2, b2, b2, d_out, 8192, 512, 2048, 1.0f, 2, Qb, flg);
}

// Round 2
// 265.174 us; speedup vs baseline: 1.1486x; 1.1486x over previous
//
#include <hip/hip_runtime.h>
#include <math.h>

typedef unsigned short ushort_t;
typedef __attribute__((ext_vector_type(4))) float floatx4;
typedef __attribute__((ext_vector_type(8))) short shortx8;
typedef __attribute__((ext_vector_type(8))) unsigned short ushortx8;

__device__ __forceinline__ float bf2f(ushort_t h) {
    union { unsigned u; float f; } x; x.u = ((unsigned)h) << 16; return x.f;
}
__device__ __forceinline__ ushort_t f2bf(float f) {
    union { float f; unsigned u; } x; x.f = f;
    unsigned r = x.u + 0x7fffu + ((x.u >> 16) & 1u);
    return (ushort_t)(r >> 16);
}
__device__ __forceinline__ float rdIn(const void* p, size_t i, int f32) {
    return f32 ? ((const float*)p)[i] : bf2f(((const ushort_t*)p)[i]);
}
// async global->LDS DMA, 16 B per lane (dest must be wave-uniform base + lane*16)
__device__ __forceinline__ void gload16(const ushort_t* g, ushort_t* l) {
    __builtin_amdgcn_global_load_lds(
        (const __attribute__((address_space(1))) unsigned int*)g,
        (__attribute__((address_space(3))) unsigned int*)l, 16, 0, 0);
}
// branch-free GELU: erf via Abramowitz-Stegun 7.1.26 (|erf err| <= 1.5e-7)
__device__ __forceinline__ float gelu_f(float v) {
    float z = fabsf(v) * 0.70710678118654752f;
    float t = __builtin_amdgcn_rcpf(1.0f + 0.3275911f * z);
    float p = 1.061405429f;
    p = p * t - 1.453152027f;
    p = p * t + 1.421413741f;
    p = p * t - 0.284496736f;
    p = p * t + 0.254829592f;
    p = p * t;
    float er = 1.0f - p * __expf(-z * z);
    er = copysignf(er, v);
    return 0.5f * v * (1.0f + er);
}

// ---------------- dtype detect: bf16 vs fp32 --------------------------------
__global__ __launch_bounds__(256) void detect_kernel(const ushort_t* __restrict__ x,
                                                     int* __restrict__ flag) {
    __shared__ int cnt;
    if (threadIdx.x == 0) cnt = 0;
    __syncthreads();
    ushort_t v = x[threadIdx.x];
    int e = (v >> 7) & 0xff;
    int ok = (e >= 100 && e <= 150) || (v == 0);
    atomicAdd(&cnt, ok);
    __syncthreads();
    if (threadIdx.x == 0) flag[0] = (cnt >= 240) ? 0 : 1;   // 0=bf16, 1=fp32
}

// ---------------- prep: x [2,4095,512] raw -> Xp [2,4096,512] bf16 ----------
__global__ __launch_bounds__(256) void prep_kernel(const void* __restrict__ x,
                                                   ushort_t* __restrict__ Xp,
                                                   const int* __restrict__ flag) {
    const int f32 = flag[0];
    int i = blockIdx.x * 256 + threadIdx.x;
    int e = i * 8;
    int s = (e >> 9) & 4095;
    int b = e >> 21;
    ushortx8 val = {0, 0, 0, 0, 0, 0, 0, 0};
    if (s < 4095) {
        size_t src = ((size_t)(b * 4095 + s) << 9) + (e & 511);
        if (f32) {
            const float* p = (const float*)x + src;
            floatx4 a = *(const floatx4*)p;
            floatx4 c = *(const floatx4*)(p + 4);
            val[0] = f2bf(a[0]); val[1] = f2bf(a[1]); val[2] = f2bf(a[2]); val[3] = f2bf(a[3]);
            val[4] = f2bf(c[0]); val[5] = f2bf(c[1]); val[6] = f2bf(c[2]); val[7] = f2bf(c[3]);
        } else {
            val = *(const ushortx8*)((const ushort_t*)x + src);
        }
    }
    *(ushortx8*)&Xp[e] = val;
}

// ---------------- transpose raw weight [R,C] -> bf16 [C,R] ------------------
__global__ __launch_bounds__(256) void transpose_kernel(
    const void* __restrict__ in0, const void* __restrict__ in1,
    const void* __restrict__ in2, ushort_t* __restrict__ out,
    int R, int C, const int* __restrict__ flag) {
    const int f32 = flag[0];
    const int z = blockIdx.z;
    const void* in = (z == 0) ? in0 : (z == 1) ? in1 : in2;
    __shared__ ushort_t tile[32][33];
    int c0 = blockIdx.x * 32, r0 = blockIdx.y * 32;
    int tx = threadIdx.x & 31, ty = threadIdx.x >> 5;
#pragma unroll
    for (int i = 0; i < 4; i++) {
        size_t idx = (size_t)(r0 + ty + 8 * i) * C + c0 + tx;
        tile[ty + 8 * i][tx] = f32 ? f2bf(((const float*)in)[idx])
                                   : ((const ushort_t*)in)[idx];
    }
    __syncthreads();
#pragma unroll
    for (int i = 0; i < 4; i++)
        out[(size_t)z * R * C + (size_t)(c0 + ty + 8 * i) * R + r0 + tx] =
            tile[tx][ty + 8 * i];
}

// ---------------- legacy GEMM (MLP2, N=512): C = A @ Bt^T -------------------
#define BM 128
#define BK 32

template<int TBN>
__global__ __launch_bounds__(256) void gemm_bt_kernel(
    const ushort_t* __restrict__ A, const ushort_t* __restrict__ Bt,
    const void* __restrict__ bias0, const void* __restrict__ bias1,
    const void* __restrict__ bias2, void* outp,
    int M, int N, int K, float scale, int epi,
    const ushort_t* __restrict__ resid, const int* __restrict__ flag) {
    constexpr int TN = TBN / 32;             // col tiles per wave
    const int f32 = flag[0];
    __shared__ __align__(16) ushort_t As[2][BM][BK];
    __shared__ __align__(16) ushort_t Bs[2][TBN][BK];
    const int m0 = blockIdx.x * BM, n0 = blockIdx.y * TBN;
    const int t = threadIdx.x;
    const int lane = t & 63, wave = t >> 6;
    const int wr = wave >> 1, wc = wave & 1;
    const int quad = lane >> 4, l16 = lane & 15;
    const int srow = t >> 2, schunk = (t & 3) * 8;

    const ushort_t* Ag = A + (size_t)(m0 + srow) * K + schunk;
    const ushort_t* Bg = Bt + (size_t)(n0 + srow) * K + schunk;

    floatx4 acc[4][TN];
#pragma unroll
    for (int i = 0; i < 4; i++)
#pragma unroll
        for (int j = 0; j < TN; j++)
#pragma unroll
            for (int r = 0; r < 4; r++) acc[i][j][r] = 0.f;

    // preload tile 0 into buf 0
    gload16(Ag,                  &As[0][srow][schunk]);
    gload16(Ag + (size_t)64 * K, &As[0][srow + 64][schunk]);
    gload16(Bg,                  &Bs[0][srow][schunk]);
    if (TBN == 128)
        gload16(Bg + (size_t)64 * K, &Bs[0][srow + 64][schunk]);

    const int KT = K / BK;
    for (int kt = 0; kt < KT; kt++) {
        __syncthreads();
        if (kt + 1 < KT) {
            int nb = (kt + 1) & 1;
            const ushort_t* Ag2 = Ag + (kt + 1) * BK;
            const ushort_t* Bg2 = Bg + (kt + 1) * BK;
            gload16(Ag2,                  &As[nb][srow][schunk]);
            gload16(Ag2 + (size_t)64 * K, &As[nb][srow + 64][schunk]);
            gload16(Bg2,                  &Bs[nb][srow][schunk]);
            if (TBN == 128)
                gload16(Bg2 + (size_t)64 * K, &Bs[nb][srow + 64][schunk]);
        }
        const int cb = kt & 1;
        shortx8 af[4], bfr[TN];
#pragma unroll
        for (int tm = 0; tm < 4; tm++)
            af[tm] = *(const shortx8*)&As[cb][wr * 64 + tm * 16 + l16][quad * 8];
#pragma unroll
        for (int tn = 0; tn < TN; tn++)
            bfr[tn] = *(const shortx8*)&Bs[cb][wc * (TBN / 2) + tn * 16 + l16][quad * 8];
#pragma unroll
        for (int tm = 0; tm < 4; tm++)
#pragma unroll
            for (int tn = 0; tn < TN; tn++)
                acc[tm][tn] = __builtin_amdgcn_mfma_f32_16x16x32_bf16(
                    af[tm], bfr[tn], acc[tm][tn], 0, 0, 0);
    }

#pragma unroll
    for (int tm = 0; tm < 4; tm++) {
#pragma unroll
        for (int tn = 0; tn < TN; tn++) {
#pragma unroll
            for (int r = 0; r < 4; r++) {
                int m = m0 + wr * 64 + tm * 16 + quad * 4 + r;
                int n = n0 + wc * (TBN / 2) + tn * 16 + l16;
                float v = acc[tm][tn][r];
                if (epi == 3) {
                    int idx = n >> 9, off = n & 511;
                    const void* bp = (idx == 0) ? bias0 : (idx == 1) ? bias1 : bias2;
                    float bb = rdIn(bp, off, f32);
                    float sc = (idx == 0) ? scale : 1.0f;
                    ((ushort_t*)outp)[(size_t)idx * 4194304 + (size_t)m * 512 + off] =
                        f2bf((v + bb) * sc);
                } else if (epi == 1) {
                    v += rdIn(bias0, n, f32);
                    ((ushort_t*)outp)[(size_t)m * N + n] = f2bf(gelu_f(v));
                } else {
                    int bb2 = m >> 12, s = m & 4095;
                    if (s < 4095) {
                        v += rdIn(bias0, n, f32) + bf2f(resid[(size_t)m * N + n]);
                        size_t oidx = ((size_t)bb2 * 4095 + s) * (size_t)N + n;
                        if (f32) ((float*)outp)[oidx] = v;
                        else     ((ushort_t*)outp)[oidx] = f2bf(v);
                    }
                }
            }
        }
    }
}

// ---------------- 8-phase 256x256 GEMM (QKV, MLP1; K=512) -------------------
// m201-style schedule in plain HIP. BK=64 split as 2 ks-halves (K=32 each).
// 512 thr = 8 waves (2Mx4N), wave tile 128x64, acc[8][4].
// LDS (128 KiB): A[2 buf][2 ks][256 rows][64 B], then B same at +64 KiB.
//   ks-plane-major so each half-tile is LINEAR for global_load_lds.
// Chunk swizzle: phys16Bchunk = logical ^ ((row>>1)&3), applied at global
//   source (DMA writes linearly) and at ds_read -> conflict-free b128 reads.
// Per K-tile: 4 phases {stage 2 gloads | ds_read 4-8 b128 | setprio 16 MFMA};
//   waits are vmcnt(4) (half-tile granularity, never 0 until tail);
//   2 barriers per K-tile. Ring of 2 tiles, stage-ahead-1.
// Epilogue: bias(+gelu/scale) on acc, bounce C through LDS (XOR-swizzled),
//   re-read row-major, 16-B coalesced global stores.
template<int EPI>  // 3 = QKV merged out, 1 = gelu(out)
__global__ __launch_bounds__(512, 2) void gemm8p_kernel(
    const ushort_t* __restrict__ A, const ushort_t* __restrict__ Bt,
    const void* __restrict__ bias0, const void* __restrict__ bias1,
    const void* __restrict__ bias2, void* outp,
    int M, int N, int K, float scale, const int* __restrict__ flag) {
    const int f32 = flag[0];
    __shared__ __align__(16) ushort_t SH[65536];   // 128 KiB
    // ushort offsets: A plane: buf*16384 + ks*8192 ; B: +32768
    const int t = threadIdx.x;
    const int lane = t & 63, wave = t >> 6;
    const int wr = wave >> 2, wc = wave & 3;       // 2 x 4 wave grid
    const int l16 = lane & 15, quad = lane >> 4;
    const int pc16 = (quad ^ ((l16 >> 1) & 3)) * 8;  // swizzled 16B chunk (ushorts)

    // XCD-aware block swizzle (grids are multiples of 8)
    const int gx = gridDim.x;
    int nwg = gx * gridDim.y;
    int bid = blockIdx.x + gx * blockIdx.y;
    int cpx = nwg >> 3;
    int sb = (bid & 7) * cpx + (bid >> 3);
    const int m0 = (sb % gx) * 256;
    const int n0 = (sb / gx) * 256;

    // staging: thread t covers rows t>>2 and t>>2+128 of one ks half-plane
    const int sr = t >> 2;
    const int lc = ((t & 3) ^ ((t >> 3) & 3)) * 8;   // pre-swizzled source chunk
    const ushort_t* Ag = A + (size_t)(m0 + sr) * K + lc;
    const ushort_t* Bg = Bt + (size_t)(n0 + sr) * K + lc;
    ushort_t* Sd = SH + t * 8;

    auto STAGE_A = [&](int buf, int kt, int ks) {
        const ushort_t* g = Ag + kt * 64 + ks * 32;
        int d = buf * 16384 + ks * 8192;
        gload16(g,                   Sd + d);
        gload16(g + (size_t)128 * K, Sd + d + 4096);
    };
    auto STAGE_B = [&](int buf, int kt, int ks) {
        const ushort_t* g = Bg + kt * 64 + ks * 32;
        int d = 32768 + buf * 16384 + ks * 8192;
        gload16(g,                   Sd + d);
        gload16(g + (size_t)128 * K, Sd + d + 4096);
    };

    floatx4 acc[8][4];
#pragma unroll
    for (int i = 0; i < 8; i++)
#pragma unroll
        for (int j = 0; j < 4; j++)
#pragma unroll
            for (int r = 0; r < 4; r++) acc[i][j][r] = 0.f;

    shortx8 af[4], bfr[4];
    auto LDB = [&](int buf, int ks) {
#pragma unroll
        for (int nf = 0; nf < 4; nf++)
            bfr[nf] = *(const shortx8*)&SH[32768 + buf * 16384 + ks * 8192 +
                                           (wc * 64 + nf * 16 + l16) * 32 + pc16];
    };
    auto LDA = [&](int buf, int ks, int h) {
#pragma unroll
        for (int i = 0; i < 4; i++)
            af[i] = *(const shortx8*)&SH[buf * 16384 + ks * 8192 +
                                         (wr * 128 + (h * 4 + i) * 16 + l16) * 32 + pc16];
    };
    auto FMA = [&](int h) {
        __builtin_amdgcn_s_setprio(1);
#pragma unroll
        for (int i = 0; i < 4; i++)
#pragma unroll
            for (int nf = 0; nf < 4; nf++)
                acc[h * 4 + i][nf] = __builtin_amdgcn_mfma_f32_16x16x32_bf16(
                    af[i], bfr[nf], acc[h * 4 + i][nf], 0, 0, 0);
        __builtin_amdgcn_s_setprio(0);
    };

    const int KT = K / 64;
    // prologue: tile 0, issue order = wait order (ks0 A,B then ks1 A,B)
    STAGE_A(0, 0, 0); STAGE_B(0, 0, 0);
    STAGE_A(0, 0, 1); STAGE_B(0, 0, 1);

    for (int kt = 0; kt < KT; kt++) {
        const int b = kt & 1, nb = b ^ 1;
        const bool pf = (kt + 1 < KT);
        // P1: need ks0(kt) = oldest 4 loads; ks1(kt) stays in flight
        asm volatile("s_waitcnt vmcnt(4)" ::: "memory");
        __builtin_amdgcn_s_barrier();
        asm volatile("" ::: "memory");
        if (pf) STAGE_A(nb, kt + 1, 0);
        LDB(b, 0); LDA(b, 0, 0);
        FMA(0);
        // P2
        if (pf) STAGE_B(nb, kt + 1, 0);
        LDA(b, 0, 1);
        FMA(1);
        // P3: need ks1(kt); outstanding = ks1(kt)4 + ks0(kt+1)4 (if pf)
        if (pf) asm volatile("s_waitcnt vmcnt(4)" ::: "memory");
        else    asm volatile("s_waitcnt vmcnt(0)" ::: "memory");
        __builtin_amdgcn_s_barrier();
        asm volatile("" ::: "memory");
        if (pf) STAGE_A(nb, kt + 1, 1);
        LDB(b, 1); LDA(b, 1, 0);
        FMA(0);
        // P4
        if (pf) STAGE_B(nb, kt + 1, 1);
        LDA(b, 1, 1);
        FMA(1);
    }

    // ---------------- epilogue: process acc, bounce via LDS, coalesced store
    __syncthreads();   // all LDS reads done before overwrite

    float bias[4];
    float scl = 1.0f;
    if (EPI == 3) {
        int idx = n0 >> 9;
        const void* bp = (idx == 0) ? bias0 : (idx == 1) ? bias1 : bias2;
#pragma unroll
        for (int nf = 0; nf < 4; nf++)
            bias[nf] = rdIn(bp, (n0 & 511) + wc * 64 + nf * 16 + l16, f32);
        scl = (idx == 0) ? scale : 1.0f;
    } else {
#pragma unroll
        for (int nf = 0; nf < 4; nf++)
            bias[nf] = rdIn(bias0, n0 + wc * 64 + nf * 16 + l16, f32);
    }

#pragma unroll
    for (int mf = 0; mf < 8; mf++) {
#pragma unroll
        for (int nf = 0; nf < 4; nf++) {
#pragma unroll
            for (int r = 0; r < 4; r++) {
                int row = wr * 128 + mf * 16 + quad * 4 + r;
                float v = acc[mf][nf][r] + bias[nf];
                if (EPI == 3) v *= scl;
                else          v = gelu_f(v);
                int ch = wc * 8 + nf * 2 + (l16 >> 3);
                SH[row * 256 + ((ch ^ (row & 7)) * 8) + (l16 & 7)] = f2bf(v);
            }
        }
    }
    __syncthreads();

    if (EPI == 3) {
        ushort_t* ob = (ushort_t*)outp + (size_t)(n0 >> 9) * 4194304 + (n0 & 511);
#pragma unroll
        for (int i = 0; i < 16; i++) {
            int j = i * 512 + t;
            int row = j >> 5, ch = j & 31;
            ushortx8 vv = *(const ushortx8*)&SH[row * 256 + ((ch ^ (row & 7)) * 8)];
            *(ushortx8*)&ob[(size_t)(m0 + row) * 512 + ch * 8] = vv;
        }
    } else {
        ushort_t* ob = (ushort_t*)outp + n0;
#pragma unroll
        for (int i = 0; i < 16; i++) {
            int j = i * 512 + t;
            int row = j >> 5, ch = j & 31;
            ushortx8 vv = *(const ushortx8*)&SH[row * 256 + ((ch ^ (row & 7)) * 8)];
            *(ushortx8*)&ob[(size_t)(m0 + row) * N + ch * 8] = vv;
        }
    }
}

// ---------------- MFMA windowed attention + global key ----------------------
#define ALD 344

__global__ __launch_bounds__(256) void attn_mfma_kernel(
    ushort_t* Q, const ushort_t* __restrict__ Kx, const ushort_t* __restrict__ Vx) {
    __shared__ ushort_t Pl[64][ALD];
    __shared__ ushort_t Vt[2][64][40];
    __shared__ float pgl[64];

    const int t = threadIdx.x;
    const int lane = t & 63, w = t >> 6;
    const int l16 = lane & 15, quad = lane >> 4;
    const int bid = blockIdx.x;
    const int qt = bid & 63;
    const int h = (bid >> 6) & 7;
    const int b = bid >> 9;
    const int q0 = qt * 64;
    const int jmin = q0 - 128;
    const size_t base = ((size_t)b * 4096) * 512 + (size_t)h * 64;

    const int qw = q0 + w * 16;
    const int lo = qw - 128, hi = qw + 15 + 128;

    shortx8 qf0, qf1;
    {
        const ushort_t* qp = Q + base + (size_t)(qw + l16) * 512 + quad * 8;
        qf0 = *(const shortx8*)(qp);
        qf1 = *(const shortx8*)(qp + 32);
    }

    floatx4 s[21];
#pragma unroll
    for (int i = 0; i < 21; i++)
#pragma unroll
        for (int r = 0; r < 4; r++) s[i][r] = 0.f;

#pragma unroll
    for (int tt = 0; tt < 20; tt++) {
        int jt = jmin + tt * 16;
        if (jt + 15 < lo || jt > hi) continue;
        int key = jt + l16;
        int kcl = min(max(key, 0), 4094);
        const ushort_t* kp = Kx + base + (size_t)kcl * 512 + quad * 8;
        shortx8 k0 = *(const shortx8*)(kp);
        shortx8 k1 = *(const shortx8*)(kp + 32);
        s[tt] = __builtin_amdgcn_mfma_f32_16x16x32_bf16(qf0, k0, s[tt], 0, 0, 0);
        s[tt] = __builtin_amdgcn_mfma_f32_16x16x32_bf16(qf1, k1, s[tt], 0, 0, 0);
    }
    {
        const ushort_t* kp = Kx + base + (size_t)4095 * 512 + quad * 8;
        shortx8 k0 = *(const shortx8*)(kp);
        shortx8 k1 = *(const shortx8*)(kp + 32);
        s[20] = __builtin_amdgcn_mfma_f32_16x16x32_bf16(qf0, k0, s[20], 0, 0, 0);
        s[20] = __builtin_amdgcn_mfma_f32_16x16x32_bf16(qf1, k1, s[20], 0, 0, 0);
    }

#pragma unroll
    for (int tt = 0; tt < 20; tt++) {
        int j = jmin + tt * 16 + l16;
        bool okj = (j >= 0) && (j <= 4094);
#pragma unroll
        for (int r = 0; r < 4; r++) {
            int q = qw + quad * 4 + r;
            bool ok = okj && (j - q <= 128) && (q - j <= 128);
            if (!ok) s[tt][r] = -1e30f;
        }
    }
    if (l16 != 0) {
#pragma unroll
        for (int r = 0; r < 4; r++) s[20][r] = -1e30f;
    }

    floatx4 mx = s[0];
#pragma unroll
    for (int tt = 1; tt < 21; tt++)
#pragma unroll
        for (int r = 0; r < 4; r++) mx[r] = fmaxf(mx[r], s[tt][r]);
#pragma unroll
    for (int off = 1; off < 16; off <<= 1)
#pragma unroll
        for (int r = 0; r < 4; r++) mx[r] = fmaxf(mx[r], __shfl_xor(mx[r], off, 64));

    floatx4 sum;
#pragma unroll
    for (int r = 0; r < 4; r++) sum[r] = 0.f;
#pragma unroll
    for (int tt = 0; tt < 21; tt++)
#pragma unroll
        for (int r = 0; r < 4; r++) {
            float e = __expf(s[tt][r] - mx[r]);
            s[tt][r] = e;
            sum[r] += e;
        }
#pragma unroll
    for (int off = 1; off < 16; off <<= 1)
#pragma unroll
        for (int r = 0; r < 4; r++) sum[r] += __shfl_xor(sum[r], off, 64);

    floatx4 inv;
#pragma unroll
    for (int r = 0; r < 4; r++) inv[r] = 1.f / sum[r];

#pragma unroll
    for (int tt = 0; tt < 20; tt++)
#pragma unroll
        for (int r = 0; r < 4; r++)
            Pl[w * 16 + quad * 4 + r][tt * 16 + l16] = f2bf(s[tt][r]);
    if (l16 == 0) {
#pragma unroll
        for (int r = 0; r < 4; r++) pgl[w * 16 + quad * 4 + r] = s[20][r];
    }

    floatx4 o[4];
#pragma unroll
    for (int nt = 0; nt < 4; nt++)
#pragma unroll
        for (int r = 0; r < 4; r++) o[nt][r] = 0.f;

    const int ck = t & 31, cd = t >> 5;
    ushortx8 vreg;
    {
        int row = min(max(jmin + ck, 0), 4095);
        vreg = *(const ushortx8*)&Vx[base + (size_t)row * 512 + cd * 8];
    }
    for (int c = 0; c < 10; c++) {
#pragma unroll
        for (int e = 0; e < 8; e++) Vt[c & 1][cd * 8 + e][ck] = vreg[e];
        if (c < 9) {
            int row = min(max(jmin + (c + 1) * 32 + ck, 0), 4095);
            vreg = *(const ushortx8*)&Vx[base + (size_t)row * 512 + cd * 8];
        }
        __syncthreads();
        int jc = jmin + c * 32;
        if (jc + 31 >= lo && jc <= hi) {
            shortx8 pf = *(const shortx8*)&Pl[w * 16 + l16][c * 32 + quad * 8];
#pragma unroll
            for (int nt = 0; nt < 4; nt++) {
                shortx8 vf = *(const shortx8*)&Vt[c & 1][nt * 16 + l16][quad * 8];
                o[nt] = __builtin_amdgcn_mfma_f32_16x16x32_bf16(pf, vf, o[nt], 0, 0, 0);
            }
        }
    }

#pragma unroll
    for (int nt = 0; nt < 4; nt++) {
        float vg = bf2f(Vx[base + (size_t)4095 * 512 + nt * 16 + l16]);
#pragma unroll
        for (int r = 0; r < 4; r++) {
            float pg = pgl[w * 16 + quad * 4 + r];
            float val = (o[nt][r] + pg * vg) * inv[r];
            Q[base + (size_t)(qw + quad * 4 + r) * 512 + nt * 16 + l16] = f2bf(val);
        }
    }
}

// ---------------- residual + LayerNorm, in-place on hio ---------------------
__global__ __launch_bounds__(256) void ln_kernel(
    const void* __restrict__ x, ushort_t* hio,
    const void* __restrict__ g, const void* __restrict__ bta,
    const int* __restrict__ flag) {
    const int f32 = flag[0];
    const int r = blockIdx.x;
    const int b = (r >= 4095) ? 1 : 0;
    const int s = r - b * 4095;
    const size_t xrow = (size_t)r * 512;
    const size_t hrow = ((size_t)b * 4096 + s) * 512;
    const int t = threadIdx.x;
    float h0 = rdIn(x, xrow + t, f32) + bf2f(hio[hrow + t]);
    float h1 = rdIn(x, xrow + 256 + t, f32) + bf2f(hio[hrow + 256 + t]);
    float sum = h0 + h1, sq = h0 * h0 + h1 * h1;
#pragma unroll
    for (int off = 1; off < 64; off <<= 1) {
        sum += __shfl_xor(sum, off, 64);
        sq += __shfl_xor(sq, off, 64);
    }
    __shared__ float red[8];
    int wave = t >> 6, lane = t & 63;
    if (lane == 0) { red[wave] = sum; red[wave + 4] = sq; }
    __syncthreads();
    sum = red[0] + red[1] + red[2] + red[3];
    sq = red[4] + red[5] + red[6] + red[7];
    float mu = sum * (1.f / 512.f);
    float var = sq * (1.f / 512.f) - mu * mu;
    float rs = rsqrtf(var + 1e-5f);
    float v0 = (h0 - mu) * rs * rdIn(g, t, f32) + rdIn(bta, t, f32);
    float v1 = (h1 - mu) * rs * rdIn(g, 256 + t, f32) + rdIn(bta, 256 + t, f32);
    hio[hrow + t] = f2bf(v0);
    hio[hrow + 256 + t] = f2bf(v1);
}

// ---------------- launch -----------------------------------------------------
// ws layout (peak 47,710,212 B; ws_size proven >= this in round 5/6):
//   Qb[0) Kb[8.39M) Vb[16.78M)
//   Xp[33.55M..41.94M)  bf16 x, dead after QKV GEMM
//   Gs[8.39M..41.94M)   MLP strip, written after Xp is dead
//   Wqt[41.94M) W1t[43.52M) W2t[45.61M) flag[47.71M)
extern "C" void kernel_launch(void* const* d_in, const int* in_sizes, int n_in,
                              void* d_out, int out_size, void* d_ws, size_t ws_size,
                              hipStream_t stream) {
    const void* x   = d_in[0];
    const void* Wq  = d_in[2];
    const void* bq  = d_in[3];
    const void* Wk  = d_in[4];
    const void* bk  = d_in[5];
    const void* Wv  = d_in[6];
    const void* bv  = d_in[7];
    const void* lng = d_in[14];
    const void* lnb = d_in[15];
    const void* W1  = d_in[16];
    const void* b1  = d_in[17];
    const void* W2  = d_in[18];
    const void* b2  = d_in[19];

    char* ws = (char*)d_ws;
    ushort_t* Qb  = (ushort_t*)(ws + 0);
    ushort_t* Kb  = (ushort_t*)(ws + 8388608);
    ushort_t* Vb  = (ushort_t*)(ws + 16777216);
    ushort_t* Xp  = (ushort_t*)(ws + 33554432);
    ushort_t* Gs  = (ushort_t*)(ws + 8388608);
    ushort_t* Wqt = (ushort_t*)(ws + 41943040);
    ushort_t* W1t = (ushort_t*)(ws + 43515904);
    ushort_t* W2t = (ushort_t*)(ws + 45613056);
    int*      flg = (int*)(ws + 47710208);

    detect_kernel<<<dim3(1), dim3(256), 0, stream>>>((const ushort_t*)x, flg);

    transpose_kernel<<<dim3(16, 16, 3), dim3(256), 0, stream>>>(Wq, Wk, Wv, Wqt, 512, 512, flg);
    transpose_kernel<<<dim3(64, 16, 1), dim3(256), 0, stream>>>(W1, W1, W1, W1t, 512, 2048, flg);
    transpose_kernel<<<dim3(16, 64, 1), dim3(256), 0, stream>>>(W2, W2, W2, W2t, 2048, 512, flg);

    prep_kernel<<<dim3(2048), dim3(256), 0, stream>>>(x, Xp, flg);

    const float scale = 0.125f;  // 1/sqrt(64)
    gemm8p_kernel<3><<<dim3(32, 6), dim3(512), 0, stream>>>(
        Xp, Wqt, bq, bk, bv, Qb, 8192, 1536, 512, scale, flg);

    attn_mfma_kernel<<<dim3(1024), dim3(256), 0, stream>>>(Qb, Kb, Vb);

    ln_kernel<<<dim3(8190), dim3(256), 0, stream>>>(x, Qb, lng, lnb, flg);

    gemm8p_kernel<1><<<dim3(32, 8), dim3(512), 0, stream>>>(
        Qb, W1t, b1, b1, b1, Gs, 8192, 2048, 512, 1.0f, flg);
    gemm_bt_kernel<64><<<dim3(64, 8), dim3(256), 0, stream>>>(
        Gs, W2t, b2, b2, b2, d_out, 8192, 512, 2048, 1.0f, 2, Qb, flg);
}

// Round 4
// 261.138 us; speedup vs baseline: 1.1663x; 1.0155x over previous
//
#include <hip/hip_runtime.h>
#include <math.h>

typedef unsigned short ushort_t;
typedef __attribute__((ext_vector_type(4))) float floatx4;
typedef __attribute__((ext_vector_type(8))) short shortx8;
typedef __attribute__((ext_vector_type(8))) unsigned short ushortx8;

__device__ __forceinline__ float bf2f(ushort_t h) {
    union { unsigned u; float f; } x; x.u = ((unsigned)h) << 16; return x.f;
}
__device__ __forceinline__ ushort_t f2bf(float f) {
    union { float f; unsigned u; } x; x.f = f;
    unsigned r = x.u + 0x7fffu + ((x.u >> 16) & 1u);
    return (ushort_t)(r >> 16);
}
__device__ __forceinline__ float rdIn(const void* p, size_t i, int f32) {
    return f32 ? ((const float*)p)[i] : bf2f(((const ushort_t*)p)[i]);
}
// async global->LDS DMA, 16 B per lane (dest must be wave-uniform base + lane*16)
__device__ __forceinline__ void gload16(const ushort_t* g, ushort_t* l) {
    __builtin_amdgcn_global_load_lds(
        (const __attribute__((address_space(1))) unsigned int*)g,
        (__attribute__((address_space(3))) unsigned int*)l, 16, 0, 0);
}
// branch-free GELU: erf via Abramowitz-Stegun 7.1.26 (|erf err| <= 1.5e-7)
__device__ __forceinline__ float gelu_f(float v) {
    float z = fabsf(v) * 0.70710678118654752f;
    float t = __builtin_amdgcn_rcpf(1.0f + 0.3275911f * z);
    float p = 1.061405429f;
    p = p * t - 1.453152027f;
    p = p * t + 1.421413741f;
    p = p * t - 0.284496736f;
    p = p * t + 0.254829592f;
    p = p * t;
    float er = 1.0f - p * __expf(-z * z);
    er = copysignf(er, v);
    return 0.5f * v * (1.0f + er);
}

// ---------------- dtype detect: bf16 vs fp32 --------------------------------
__global__ __launch_bounds__(256) void detect_kernel(const ushort_t* __restrict__ x,
                                                     int* __restrict__ flag) {
    __shared__ int cnt;
    if (threadIdx.x == 0) cnt = 0;
    __syncthreads();
    ushort_t v = x[threadIdx.x];
    int e = (v >> 7) & 0xff;
    int ok = (e >= 100 && e <= 150) || (v == 0);
    atomicAdd(&cnt, ok);
    __syncthreads();
    if (threadIdx.x == 0) flag[0] = (cnt >= 240) ? 0 : 1;   // 0=bf16, 1=fp32
}

// ---------------- prep: x [2,4095,512] raw -> Xp [2,4096,512] bf16 ----------
__global__ __launch_bounds__(256) void prep_kernel(const void* __restrict__ x,
                                                   ushort_t* __restrict__ Xp,
                                                   const int* __restrict__ flag) {
    const int f32 = flag[0];
    int i = blockIdx.x * 256 + threadIdx.x;
    int e = i * 8;
    int s = (e >> 9) & 4095;
    int b = e >> 21;
    ushortx8 val = {0, 0, 0, 0, 0, 0, 0, 0};
    if (s < 4095) {
        size_t src = ((size_t)(b * 4095 + s) << 9) + (e & 511);
        if (f32) {
            const float* p = (const float*)x + src;
            floatx4 a = *(const floatx4*)p;
            floatx4 c = *(const floatx4*)(p + 4);
            val[0] = f2bf(a[0]); val[1] = f2bf(a[1]); val[2] = f2bf(a[2]); val[3] = f2bf(a[3]);
            val[4] = f2bf(c[0]); val[5] = f2bf(c[1]); val[6] = f2bf(c[2]); val[7] = f2bf(c[3]);
        } else {
            val = *(const ushortx8*)((const ushort_t*)x + src);
        }
    }
    *(ushortx8*)&Xp[e] = val;
}

// ---------------- transpose raw weight [R,C] -> bf16 [C,R] ------------------
__global__ __launch_bounds__(256) void transpose_kernel(
    const void* __restrict__ in0, const void* __restrict__ in1,
    const void* __restrict__ in2, ushort_t* __restrict__ out,
    int R, int C, const int* __restrict__ flag) {
    const int f32 = flag[0];
    const int z = blockIdx.z;
    const void* in = (z == 0) ? in0 : (z == 1) ? in1 : in2;
    __shared__ ushort_t tile[32][33];
    int c0 = blockIdx.x * 32, r0 = blockIdx.y * 32;
    int tx = threadIdx.x & 31, ty = threadIdx.x >> 5;
#pragma unroll
    for (int i = 0; i < 4; i++) {
        size_t idx = (size_t)(r0 + ty + 8 * i) * C + c0 + tx;
        tile[ty + 8 * i][tx] = f32 ? f2bf(((const float*)in)[idx])
                                   : ((const ushort_t*)in)[idx];
    }
    __syncthreads();
#pragma unroll
    for (int i = 0; i < 4; i++)
        out[(size_t)z * R * C + (size_t)(c0 + ty + 8 * i) * R + r0 + tx] =
            tile[tx][ty + 8 * i];
}

// ---------------- 8-phase 256x256 GEMM (QKV, MLP1; K=512) -------------------
// m201-style schedule in plain HIP. BK=64 split as 2 ks-halves (K=32 each).
// 512 thr = 8 waves (2Mx4N), wave tile 128x64, acc[8][4].
// LDS (128 KiB): A[2 buf][2 ks][256 rows][64 B], then B same at +64 KiB.
// Chunk swizzle applied at global source and at ds_read chunk.
// Waits are vmcnt(4) (half-tile granularity, never 0 until tail).
template<int EPI>  // 3 = QKV merged out, 1 = gelu(out)
__global__ __launch_bounds__(512, 2) void gemm8p_kernel(
    const ushort_t* __restrict__ A, const ushort_t* __restrict__ Bt,
    const void* __restrict__ bias0, const void* __restrict__ bias1,
    const void* __restrict__ bias2, void* outp,
    int M, int N, int K, float scale, const int* __restrict__ flag) {
    const int f32 = flag[0];
    __shared__ __align__(16) ushort_t SH[65536];   // 128 KiB
    const int t = threadIdx.x;
    const int lane = t & 63, wave = t >> 6;
    const int wr = wave >> 2, wc = wave & 3;       // 2 x 4 wave grid
    const int l16 = lane & 15, quad = lane >> 4;
    const int pc16 = (quad ^ ((l16 >> 1) & 3)) * 8;  // swizzled 16B chunk (ushorts)

    // XCD-aware block swizzle (grids are multiples of 8)
    const int gx = gridDim.x;
    int nwg = gx * gridDim.y;
    int bid = blockIdx.x + gx * blockIdx.y;
    int cpx = nwg >> 3;
    int sb = (bid & 7) * cpx + (bid >> 3);
    const int m0 = (sb % gx) * 256;
    const int n0 = (sb / gx) * 256;

    const int sr = t >> 2;
    const int lc = ((t & 3) ^ ((t >> 3) & 3)) * 8;   // pre-swizzled source chunk
    const ushort_t* Ag = A + (size_t)(m0 + sr) * K + lc;
    const ushort_t* Bg = Bt + (size_t)(n0 + sr) * K + lc;
    ushort_t* Sd = SH + t * 8;

    auto STAGE_A = [&](int buf, int kt, int ks) {
        const ushort_t* g = Ag + kt * 64 + ks * 32;
        int d = buf * 16384 + ks * 8192;
        gload16(g,                   Sd + d);
        gload16(g + (size_t)128 * K, Sd + d + 4096);
    };
    auto STAGE_B = [&](int buf, int kt, int ks) {
        const ushort_t* g = Bg + kt * 64 + ks * 32;
        int d = 32768 + buf * 16384 + ks * 8192;
        gload16(g,                   Sd + d);
        gload16(g + (size_t)128 * K, Sd + d + 4096);
    };

    floatx4 acc[8][4];
#pragma unroll
    for (int i = 0; i < 8; i++)
#pragma unroll
        for (int j = 0; j < 4; j++)
#pragma unroll
            for (int r = 0; r < 4; r++) acc[i][j][r] = 0.f;

    shortx8 af[4], bfr[4];
    auto LDB = [&](int buf, int ks) {
#pragma unroll
        for (int nf = 0; nf < 4; nf++)
            bfr[nf] = *(const shortx8*)&SH[32768 + buf * 16384 + ks * 8192 +
                                           (wc * 64 + nf * 16 + l16) * 32 + pc16];
    };
    auto LDA = [&](int buf, int ks, int h) {
#pragma unroll
        for (int i = 0; i < 4; i++)
            af[i] = *(const shortx8*)&SH[buf * 16384 + ks * 8192 +
                                         (wr * 128 + (h * 4 + i) * 16 + l16) * 32 + pc16];
    };
    auto FMA = [&](int h) {
        __builtin_amdgcn_s_setprio(1);
#pragma unroll
        for (int i = 0; i < 4; i++)
#pragma unroll
            for (int nf = 0; nf < 4; nf++)
                acc[h * 4 + i][nf] = __builtin_amdgcn_mfma_f32_16x16x32_bf16(
                    af[i], bfr[nf], acc[h * 4 + i][nf], 0, 0, 0);
        __builtin_amdgcn_s_setprio(0);
    };

    const int KT = K / 64;
    STAGE_A(0, 0, 0); STAGE_B(0, 0, 0);
    STAGE_A(0, 0, 1); STAGE_B(0, 0, 1);

    for (int kt = 0; kt < KT; kt++) {
        const int b = kt & 1, nb = b ^ 1;
        const bool pf = (kt + 1 < KT);
        asm volatile("s_waitcnt vmcnt(4)" ::: "memory");
        __builtin_amdgcn_s_barrier();
        asm volatile("" ::: "memory");
        if (pf) STAGE_A(nb, kt + 1, 0);
        LDB(b, 0); LDA(b, 0, 0);
        FMA(0);
        if (pf) STAGE_B(nb, kt + 1, 0);
        LDA(b, 0, 1);
        FMA(1);
        if (pf) asm volatile("s_waitcnt vmcnt(4)" ::: "memory");
        else    asm volatile("s_waitcnt vmcnt(0)" ::: "memory");
        __builtin_amdgcn_s_barrier();
        asm volatile("" ::: "memory");
        if (pf) STAGE_A(nb, kt + 1, 1);
        LDB(b, 1); LDA(b, 1, 0);
        FMA(0);
        if (pf) STAGE_B(nb, kt + 1, 1);
        LDA(b, 1, 1);
        FMA(1);
    }

    // ---------------- epilogue: process acc, bounce via LDS, coalesced store
    __syncthreads();   // all LDS reads done before overwrite

    float bias[4];
    float scl = 1.0f;
    if (EPI == 3) {
        int idx = n0 >> 9;
        const void* bp = (idx == 0) ? bias0 : (idx == 1) ? bias1 : bias2;
#pragma unroll
        for (int nf = 0; nf < 4; nf++)
            bias[nf] = rdIn(bp, (n0 & 511) + wc * 64 + nf * 16 + l16, f32);
        scl = (idx == 0) ? scale : 1.0f;
    } else {
#pragma unroll
        for (int nf = 0; nf < 4; nf++)
            bias[nf] = rdIn(bias0, n0 + wc * 64 + nf * 16 + l16, f32);
    }

#pragma unroll
    for (int mf = 0; mf < 8; mf++) {
#pragma unroll
        for (int nf = 0; nf < 4; nf++) {
#pragma unroll
            for (int r = 0; r < 4; r++) {
                int row = wr * 128 + mf * 16 + quad * 4 + r;
                float v = acc[mf][nf][r] + bias[nf];
                if (EPI == 3) v *= scl;
                else          v = gelu_f(v);
                int ch = wc * 8 + nf * 2 + (l16 >> 3);
                SH[row * 256 + ((ch ^ (row & 7)) * 8) + (l16 & 7)] = f2bf(v);
            }
        }
    }
    __syncthreads();

    if (EPI == 3) {
        ushort_t* ob = (ushort_t*)outp + (size_t)(n0 >> 9) * 4194304 + (n0 & 511);
#pragma unroll
        for (int i = 0; i < 16; i++) {
            int j = i * 512 + t;
            int row = j >> 5, ch = j & 31;
            ushortx8 vv = *(const ushortx8*)&SH[row * 256 + ((ch ^ (row & 7)) * 8)];
            *(ushortx8*)&ob[(size_t)(m0 + row) * 512 + ch * 8] = vv;
        }
    } else {
        ushort_t* ob = (ushort_t*)outp + n0;
#pragma unroll
        for (int i = 0; i < 16; i++) {
            int j = i * 512 + t;
            int row = j >> 5, ch = j & 31;
            ushortx8 vv = *(const ushortx8*)&SH[row * 256 + ((ch ^ (row & 7)) * 8)];
            *(ushortx8*)&ob[(size_t)(m0 + row) * N + ch * 8] = vv;
        }
    }
}

// ---------------- split-K 128x128 GEMM for MLP2 (M=8192,N=512,K=2048) -------
// grid 256 = 64 mt x 4 nt (XCD-aware), 512 thr = 8 waves:
//   wave w: kh=w>>2 (K-half), wr=(w>>1)&1, wc=w&1 -> 64x64 subtile, acc[4][4].
// Each kh accumulates K in [kh*1024, kh*1024+1024), BK=32/step, KT=32 deep.
// 4-deep LDS ring (A/B planes 8 KB each, 128 KiB total), counted vmcnt(8)
// steady state, one s_barrier per step, setprio around the 16-MFMA cluster.
// Chunk-XOR swizzle identical to gemm8p (reads are a bijection over 1 KB).
// Epilogue: kh1 waves dump fp32 acc to LDS, kh0 adds -> no HBM partials;
// then epi-2 semantics: +bias +resid, skip padded row, fp32/bf16 out.
__global__ __launch_bounds__(512, 2) void gemm_splitk_kernel(
    const ushort_t* __restrict__ A, const ushort_t* __restrict__ Bt,
    const void* __restrict__ bias0, void* outp,
    const ushort_t* __restrict__ resid, const int* __restrict__ flag) {
    const int f32 = flag[0];
    __shared__ __align__(16) ushort_t SH[65536];   // 128 KiB
    const int K = 2048;
    const int t = threadIdx.x;
    const int lane = t & 63, wave = t >> 6;
    const int kh = wave >> 2, wr = (wave >> 1) & 1, wc = wave & 1;
    const int l16 = lane & 15, quad = lane >> 4;
    const int pc16 = (quad ^ ((l16 >> 1) & 3)) * 8;

    // XCD-aware tile map: XCD pair shares a B panel (nt), streams 32 A panels
    const int bid = blockIdx.x;
    const int xcd = bid & 7, i5 = bid >> 3;
    const int nt = xcd >> 1;
    const int mt = (xcd & 1) * 32 + i5;
    const int m0 = mt * 128, n0 = nt * 128;

    const int sr = t >> 2;                           // 0..127
    const int lc = ((t & 3) ^ ((t >> 3) & 3)) * 8;   // pre-swizzled source chunk
    const ushort_t* Ag = A + (size_t)(m0 + sr) * K + lc;
    const ushort_t* Bg = Bt + (size_t)(n0 + sr) * K + lc;
    ushort_t* Sd = SH + t * 8;

    // LDS ushort layout: A[buf][kh]: buf*8192 + kh*4096 (plane = 128x32)
    //                    B[buf][kh]: 32768 + buf*8192 + kh*4096
    auto STAGE = [&](int kt) {
        const int b = kt & 3;
        gload16(Ag + kt * 32,        Sd + b * 8192);
        gload16(Ag + 1024 + kt * 32, Sd + b * 8192 + 4096);
        gload16(Bg + kt * 32,        Sd + 32768 + b * 8192);
        gload16(Bg + 1024 + kt * 32, Sd + 32768 + b * 8192 + 4096);
    };

    floatx4 acc[4][4];
#pragma unroll
    for (int i = 0; i < 4; i++)
#pragma unroll
        for (int j = 0; j < 4; j++)
#pragma unroll
            for (int r = 0; r < 4; r++) acc[i][j][r] = 0.f;

    const int KT = 32;
    STAGE(0); STAGE(1); STAGE(2);

    for (int kt = 0; kt < KT; kt++) {
        // tile kt must have landed; kt+1, kt+2 (8 loads) stay in flight
        if (kt + 2 < KT)      asm volatile("s_waitcnt vmcnt(8)" ::: "memory");
        else if (kt + 1 < KT) asm volatile("s_waitcnt vmcnt(4)" ::: "memory");
        else                  asm volatile("s_waitcnt vmcnt(0)" ::: "memory");
        __builtin_amdgcn_s_barrier();
        asm volatile("" ::: "memory");
        if (kt + 3 < KT) STAGE(kt + 3);   // overwrites buf[(kt-1)&3]: reads done

        const int ab = (kt & 3) * 8192 + kh * 4096;
        shortx8 af[4], bfr[4];
#pragma unroll
        for (int nf = 0; nf < 4; nf++)
            bfr[nf] = *(const shortx8*)&SH[32768 + ab + (wc * 64 + nf * 16 + l16) * 32 + pc16];
#pragma unroll
        for (int mf = 0; mf < 4; mf++)
            af[mf] = *(const shortx8*)&SH[ab + (wr * 64 + mf * 16 + l16) * 32 + pc16];

        __builtin_amdgcn_s_setprio(1);
#pragma unroll
        for (int mf = 0; mf < 4; mf++)
#pragma unroll
            for (int nf = 0; nf < 4; nf++)
                acc[mf][nf] = __builtin_amdgcn_mfma_f32_16x16x32_bf16(
                    af[mf], bfr[nf], acc[mf][nf], 0, 0, 0);
        __builtin_amdgcn_s_setprio(0);
    }

    // ---------------- in-LDS split-K reduce + epi-2 store -------------------
    __syncthreads();                       // all ds reads done before overwrite
    float* RED = (float*)SH;               // 64 KiB fp32 scratch
    if (kh == 1) {
        const int base = ((wave & 3) * 64 + lane) * 16;
#pragma unroll
        for (int i = 0; i < 4; i++)
#pragma unroll
            for (int j = 0; j < 4; j++) {
                int k2 = (i * 4 + j + l16) & 15;   // per-lane rotate: spread banks
                *(floatx4*)&RED[(base + k2) * 4] = acc[i][j];
            }
    }
    __syncthreads();
    if (kh == 0) {
        const int base = (wave * 64 + lane) * 16;
#pragma unroll
        for (int i = 0; i < 4; i++)
#pragma unroll
            for (int j = 0; j < 4; j++) {
                int k2 = (i * 4 + j + l16) & 15;
                floatx4 p = *(const floatx4*)&RED[(base + k2) * 4];
#pragma unroll
                for (int r = 0; r < 4; r++) acc[i][j][r] += p[r];
            }
#pragma unroll
        for (int i = 0; i < 4; i++) {
#pragma unroll
            for (int j = 0; j < 4; j++) {
#pragma unroll
                for (int r = 0; r < 4; r++) {
                    int m = m0 + wr * 64 + i * 16 + quad * 4 + r;
                    int n = n0 + wc * 64 + j * 16 + l16;
                    int bb = m >> 12, s = m & 4095;
                    if (s < 4095) {
                        float v = acc[i][j][r] + rdIn(bias0, n, f32) +
                                  bf2f(resid[(size_t)m * 512 + n]);
                        size_t oidx = ((size_t)bb * 4095 + s) * 512 + n;
                        if (f32) ((float*)outp)[oidx] = v;
                        else     ((ushort_t*)outp)[oidx] = f2bf(v);
                    }
                }
            }
        }
    }
}

// ---------------- MFMA windowed attention + global key ----------------------
#define ALD 344

__global__ __launch_bounds__(256) void attn_mfma_kernel(
    ushort_t* Q, const ushort_t* __restrict__ Kx, const ushort_t* __restrict__ Vx) {
    __shared__ ushort_t Pl[64][ALD];
    __shared__ ushort_t Vt[2][64][40];
    __shared__ float pgl[64];

    const int t = threadIdx.x;
    const int lane = t & 63, w = t >> 6;
    const int l16 = lane & 15, quad = lane >> 4;
    const int bid = blockIdx.x;
    const int qt = bid & 63;
    const int h = (bid >> 6) & 7;
    const int b = bid >> 9;
    const int q0 = qt * 64;
    const int jmin = q0 - 128;
    const size_t base = ((size_t)b * 4096) * 512 + (size_t)h * 64;

    const int qw = q0 + w * 16;
    const int lo = qw - 128, hi = qw + 15 + 128;

    shortx8 qf0, qf1;
    {
        const ushort_t* qp = Q + base + (size_t)(qw + l16) * 512 + quad * 8;
        qf0 = *(const shortx8*)(qp);
        qf1 = *(const shortx8*)(qp + 32);
    }

    floatx4 s[21];
#pragma unroll
    for (int i = 0; i < 21; i++)
#pragma unroll
        for (int r = 0; r < 4; r++) s[i][r] = 0.f;

#pragma unroll
    for (int tt = 0; tt < 20; tt++) {
        int jt = jmin + tt * 16;
        if (jt + 15 < lo || jt > hi) continue;
        int key = jt + l16;
        int kcl = min(max(key, 0), 4094);
        const ushort_t* kp = Kx + base + (size_t)kcl * 512 + quad * 8;
        shortx8 k0 = *(const shortx8*)(kp);
        shortx8 k1 = *(const shortx8*)(kp + 32);
        s[tt] = __builtin_amdgcn_mfma_f32_16x16x32_bf16(qf0, k0, s[tt], 0, 0, 0);
        s[tt] = __builtin_amdgcn_mfma_f32_16x16x32_bf16(qf1, k1, s[tt], 0, 0, 0);
    }
    {
        const ushort_t* kp = Kx + base + (size_t)4095 * 512 + quad * 8;
        shortx8 k0 = *(const shortx8*)(kp);
        shortx8 k1 = *(const shortx8*)(kp + 32);
        s[20] = __builtin_amdgcn_mfma_f32_16x16x32_bf16(qf0, k0, s[20], 0, 0, 0);
        s[20] = __builtin_amdgcn_mfma_f32_16x16x32_bf16(qf1, k1, s[20], 0, 0, 0);
    }

#pragma unroll
    for (int tt = 0; tt < 20; tt++) {
        int j = jmin + tt * 16 + l16;
        bool okj = (j >= 0) && (j <= 4094);
#pragma unroll
        for (int r = 0; r < 4; r++) {
            int q = qw + quad * 4 + r;
            bool ok = okj && (j - q <= 128) && (q - j <= 128);
            if (!ok) s[tt][r] = -1e30f;
        }
    }
    if (l16 != 0) {
#pragma unroll
        for (int r = 0; r < 4; r++) s[20][r] = -1e30f;
    }

    floatx4 mx = s[0];
#pragma unroll
    for (int tt = 1; tt < 21; tt++)
#pragma unroll
        for (int r = 0; r < 4; r++) mx[r] = fmaxf(mx[r], s[tt][r]);
#pragma unroll
    for (int off = 1; off < 16; off <<= 1)
#pragma unroll
        for (int r = 0; r < 4; r++) mx[r] = fmaxf(mx[r], __shfl_xor(mx[r], off, 64));

    floatx4 sum;
#pragma unroll
    for (int r = 0; r < 4; r++) sum[r] = 0.f;
#pragma unroll
    for (int tt = 0; tt < 21; tt++)
#pragma unroll
        for (int r = 0; r < 4; r++) {
            float e = __expf(s[tt][r] - mx[r]);
            s[tt][r] = e;
            sum[r] += e;
        }
#pragma unroll
    for (int off = 1; off < 16; off <<= 1)
#pragma unroll
        for (int r = 0; r < 4; r++) sum[r] += __shfl_xor(sum[r], off, 64);

    floatx4 inv;
#pragma unroll
    for (int r = 0; r < 4; r++) inv[r] = 1.f / sum[r];

#pragma unroll
    for (int tt = 0; tt < 20; tt++)
#pragma unroll
        for (int r = 0; r < 4; r++)
            Pl[w * 16 + quad * 4 + r][tt * 16 + l16] = f2bf(s[tt][r]);
    if (l16 == 0) {
#pragma unroll
        for (int r = 0; r < 4; r++) pgl[w * 16 + quad * 4 + r] = s[20][r];
    }

    floatx4 o[4];
#pragma unroll
    for (int nt = 0; nt < 4; nt++)
#pragma unroll
        for (int r = 0; r < 4; r++) o[nt][r] = 0.f;

    const int ck = t & 31, cd = t >> 5;
    ushortx8 vreg;
    {
        int row = min(max(jmin + ck, 0), 4095);
        vreg = *(const ushortx8*)&Vx[base + (size_t)row * 512 + cd * 8];
    }
    for (int c = 0; c < 10; c++) {
#pragma unroll
        for (int e = 0; e < 8; e++) Vt[c & 1][cd * 8 + e][ck] = vreg[e];
        if (c < 9) {
            int row = min(max(jmin + (c + 1) * 32 + ck, 0), 4095);
            vreg = *(const ushortx8*)&Vx[base + (size_t)row * 512 + cd * 8];
        }
        __syncthreads();
        int jc = jmin + c * 32;
        if (jc + 31 >= lo && jc <= hi) {
            shortx8 pf = *(const shortx8*)&Pl[w * 16 + l16][c * 32 + quad * 8];
#pragma unroll
            for (int nt = 0; nt < 4; nt++) {
                shortx8 vf = *(const shortx8*)&Vt[c & 1][nt * 16 + l16][quad * 8];
                o[nt] = __builtin_amdgcn_mfma_f32_16x16x32_bf16(pf, vf, o[nt], 0, 0, 0);
            }
        }
    }

#pragma unroll
    for (int nt = 0; nt < 4; nt++) {
        float vg = bf2f(Vx[base + (size_t)4095 * 512 + nt * 16 + l16]);
#pragma unroll
        for (int r = 0; r < 4; r++) {
            float pg = pgl[w * 16 + quad * 4 + r];
            float val = (o[nt][r] + pg * vg) * inv[r];
            Q[base + (size_t)(qw + quad * 4 + r) * 512 + nt * 16 + l16] = f2bf(val);
        }
    }
}

// ---------------- residual + LayerNorm, in-place on hio ---------------------
__global__ __launch_bounds__(256) void ln_kernel(
    const void* __restrict__ x, ushort_t* hio,
    const void* __restrict__ g, const void* __restrict__ bta,
    const int* __restrict__ flag) {
    const int f32 = flag[0];
    const int r = blockIdx.x;
    const int b = (r >= 4095) ? 1 : 0;
    const int s = r - b * 4095;
    const size_t xrow = (size_t)r * 512;
    const size_t hrow = ((size_t)b * 4096 + s) * 512;
    const int t = threadIdx.x;
    float h0 = rdIn(x, xrow + t, f32) + bf2f(hio[hrow + t]);
    float h1 = rdIn(x, xrow + 256 + t, f32) + bf2f(hio[hrow + 256 + t]);
    float sum = h0 + h1, sq = h0 * h0 + h1 * h1;
#pragma unroll
    for (int off = 1; off < 64; off <<= 1) {
        sum += __shfl_xor(sum, off, 64);
        sq += __shfl_xor(sq, off, 64);
    }
    __shared__ float red[8];
    int wave = t >> 6, lane = t & 63;
    if (lane == 0) { red[wave] = sum; red[wave + 4] = sq; }
    __syncthreads();
    sum = red[0] + red[1] + red[2] + red[3];
    sq = red[4] + red[5] + red[6] + red[7];
    float mu = sum * (1.f / 512.f);
    float var = sq * (1.f / 512.f) - mu * mu;
    float rs = rsqrtf(var + 1e-5f);
    float v0 = (h0 - mu) * rs * rdIn(g, t, f32) + rdIn(bta, t, f32);
    float v1 = (h1 - mu) * rs * rdIn(g, 256 + t, f32) + rdIn(bta, 256 + t, f32);
    hio[hrow + t] = f2bf(v0);
    hio[hrow + 256 + t] = f2bf(v1);
}

// ---------------- launch -----------------------------------------------------
// ws layout (peak 47,710,212 B):
//   Qb[0) Kb[8.39M) Vb[16.78M)
//   Xp[33.55M..41.94M)  bf16 x, dead after QKV GEMM
//   Gs[8.39M..41.94M)   MLP strip, written after Xp is dead
//   Wqt[41.94M) W1t[43.52M) W2t[45.61M) flag[47.71M)
extern "C" void kernel_launch(void* const* d_in, const int* in_sizes, int n_in,
                              void* d_out, int out_size, void* d_ws, size_t ws_size,
                              hipStream_t stream) {
    const void* x   = d_in[0];
    const void* Wq  = d_in[2];
    const void* bq  = d_in[3];
    const void* Wk  = d_in[4];
    const void* bk  = d_in[5];
    const void* Wv  = d_in[6];
    const void* bv  = d_in[7];
    const void* lng = d_in[14];
    const void* lnb = d_in[15];
    const void* W1  = d_in[16];
    const void* b1  = d_in[17];
    const void* W2  = d_in[18];
    const void* b2  = d_in[19];

    char* ws = (char*)d_ws;
    ushort_t* Qb  = (ushort_t*)(ws + 0);
    ushort_t* Kb  = (ushort_t*)(ws + 8388608);
    ushort_t* Vb  = (ushort_t*)(ws + 16777216);
    ushort_t* Xp  = (ushort_t*)(ws + 33554432);
    ushort_t* Gs  = (ushort_t*)(ws + 8388608);
    ushort_t* Wqt = (ushort_t*)(ws + 41943040);
    ushort_t* W1t = (ushort_t*)(ws + 43515904);
    ushort_t* W2t = (ushort_t*)(ws + 45613056);
    int*      flg = (int*)(ws + 47710208);

    detect_kernel<<<dim3(1), dim3(256), 0, stream>>>((const ushort_t*)x, flg);

    transpose_kernel<<<dim3(16, 16, 3), dim3(256), 0, stream>>>(Wq, Wk, Wv, Wqt, 512, 512, flg);
    transpose_kernel<<<dim3(64, 16, 1), dim3(256), 0, stream>>>(W1, W1, W1, W1t, 512, 2048, flg);
    transpose_kernel<<<dim3(16, 64, 1), dim3(256), 0, stream>>>(W2, W2, W2, W2t, 2048, 512, flg);

    prep_kernel<<<dim3(2048), dim3(256), 0, stream>>>(x, Xp, flg);

    const float scale = 0.125f;  // 1/sqrt(64)
    gemm8p_kernel<3><<<dim3(32, 6), dim3(512), 0, stream>>>(
        Xp, Wqt, bq, bk, bv, Qb, 8192, 1536, 512, scale, flg);

    attn_mfma_kernel<<<dim3(1024), dim3(256), 0, stream>>>(Qb, Kb, Vb);

    ln_kernel<<<dim3(8190), dim3(256), 0, stream>>>(x, Qb, lng, lnb, flg);

    gemm8p_kernel<1><<<dim3(32, 8), dim3(512), 0, stream>>>(
        Qb, W1t, b1, b1, b1, Gs, 8192, 2048, 512, 1.0f, flg);
    gemm_splitk_kernel<<<dim3(256), dim3(512), 0, stream>>>(
        Gs, W2t, b2, d_out, Qb, flg);
}